// Round 7
// baseline (462.391 us; speedup 1.0000x reference)
//
#include <hip/hip_runtime.h>
#include <math.h>

#define BB 16
#define LL 100
#define TT 50
#define TE 100
#define HH 200
#define NTL 13               // N tiles of 16 -> 208 (pad 8)
#define NBLK 1250            // grid blocks; co-resident by construction
#define NWPREP (NTL * 3 * 2048)   // 79872 weight-fragment elements
#define NEG_INF_F (-1e30f)

typedef _Float16 fp16;
typedef fp16 half8 __attribute__((ext_vector_type(8)));
typedef float f32x4 __attribute__((ext_vector_type(4)));

#define MFMA16 __builtin_amdgcn_mfma_f32_16x16x32_f16

// ---------------------------------------------------------------------------
// A-fragment gather for one flat 16-row M-tile (always valid rows, no mask).
// k = ks*32 + 8*lg + elem; ks==3 carries k=96..99 + bias-activation 1.0 @k==100.
// All array writes at compile-time indices (rule #20).
// ---------------------------------------------------------------------------
#define GATHER1(SRC, DST)                                                       \
    {                                                                           \
        _Pragma("unroll")                                                       \
        for (int ks_ = 0; ks_ < 4; ++ks_) {                                     \
            f32x4 v0 = {0.f, 0.f, 0.f, 0.f}, v1 = {0.f, 0.f, 0.f, 0.f};         \
            float one_ = 0.f;                                                   \
            if (ks_ < 3) {                                                      \
                const int d0 = ks_ * 32 + 8 * lg;                               \
                v0 = *(const f32x4*)((SRC) + d0);                               \
                v1 = *(const f32x4*)((SRC) + d0 + 4);                           \
            } else if (lg == 0) {                                               \
                v0 = *(const f32x4*)((SRC) + 96);                               \
                one_ = 1.0f;                                                    \
            }                                                                   \
            half8 h8;                                                           \
            _Pragma("unroll")                                                   \
            for (int i_ = 0; i_ < 4; ++i_) {                                    \
                h8[i_]     = (fp16)v0[i_];                                      \
                h8[4 + i_] = (fp16)v1[i_];                                      \
            }                                                                   \
            if (ks_ == 3) h8[4] = (fp16)one_;   /* k==100 activation */         \
            DST[ks_] = h8;                                                      \
        }                                                                       \
    }

// Stage 3 of the 12 1-KB units of one nt weight chunk (this wave's share).
#define STAGE3(GBASE, LBASE)                                                    \
    {                                                                           \
        _Pragma("unroll")                                                       \
        for (int u_ = 0; u_ < 3; ++u_) {                                        \
            const int unit_ = wv * 3 + u_;                                      \
            __builtin_amdgcn_global_load_lds(                                   \
                (const __attribute__((address_space(1))) unsigned int*)         \
                    ((GBASE) + unit_ * 512 + l * 8),                            \
                (__attribute__((address_space(3))) unsigned int*)               \
                    ((LBASE) + unit_ * 512),                                    \
                16, 0, 0);                                                      \
        }                                                                       \
    }

__device__ __forceinline__ void grid_barrier(unsigned* bar, int k) {
    __syncthreads();
    if (threadIdx.x == 0) {
        __threadfence();   // release my block's global writes (device scope)
        __hip_atomic_fetch_add(&bar[k], 1u, __ATOMIC_ACQ_REL,
                               __HIP_MEMORY_SCOPE_AGENT);
        unsigned tries = 0;
        while (__hip_atomic_load(&bar[k], __ATOMIC_RELAXED,
                                 __HIP_MEMORY_SCOPE_AGENT) < (unsigned)NBLK) {
            __builtin_amdgcn_s_sleep(16);
            if (++tries > 4000000u) break;   // failsafe: fail visibly, never hang
        }
        __threadfence();   // acquire other blocks' writes
    }
    __syncthreads();
}

__global__ __launch_bounds__(256, 5)
void ccm_fused_kernel(const float* __restrict__ head, const float* __restrict__ rel,
                      const float* __restrict__ tail,
                      const float* __restrict__ Whw, const float* __restrict__ Whb,
                      const float* __restrict__ Wrw, const float* __restrict__ Wrb,
                      const float* __restrict__ Wtw, const float* __restrict__ Wtb,
                      const int* __restrict__ tmask, const int* __restrict__ pmask,
                      float* __restrict__ out,
                      unsigned* __restrict__ bar,   // ws: 2 zeroed counters
                      fp16* __restrict__ WB,        // ws: weight fragments
                      float* __restrict__ score) {  // ws: 80000 f32
    __shared__ fp16 sw[2][6144];      // double-buffered nt chunk
    __shared__ float sattn[64];

    const int tid = threadIdx.x;
    const int wv  = tid >> 6;         // wave 0..3
    const int l   = tid & 63;
    const int lr  = l & 15;           // A row-in-tile / D col
    const int lg  = l >> 4;           // k-group / D row-group

    // ================= phase 0: weight prep (grid-strided) =================
    {
        const int idx = blockIdx.x * 256 + tid;
        if (idx < NWPREP) {
            const int elem = idx & 7;
            const int lane = (idx >> 3) & 63;
            const int ks   = (idx >> 9) & 3;
            const int np   = idx >> 11;     // nt*3 + p
            const int p    = np % 3;
            const int nt   = np / 3;
            const int k = ks * 32 + 8 * (lane >> 4) + elem;
            const int n = nt * 16 + (lane & 15);
            const float* W  = (p == 0) ? Whw : (p == 1) ? Wrw : Wtw;
            const float* Bi = (p == 0) ? Whb : (p == 1) ? Wrb : Wtb;
            float v = 0.0f;
            if (n < HH) {
                if (k < TE)       v = W[n * TE + k];
                else if (k == TE) v = Bi[n];        // bias row (A supplies 1.0)
            }
            WB[idx] = (fp16)v;
        }
    }
    grid_barrier(bar, 0);

    // ================= phase A: flat-M GEMM + score =================
    // wave -> one 16-row M-tile; 1250 blocks * 4 waves = 5000 tiles = 80000 rows
    {
        const int wtile = blockIdx.x * 4 + wv;
        const size_t abase = ((size_t)wtile * 16 + lr) * TE;

        half8 HA[4], RA[4], TA[4];
        GATHER1(head + abase, HA);
        GATHER1(rel  + abase, RA);
        GATHER1(tail + abase, TA);

        STAGE3(WB, &sw[0][0]);

        float sc[4] = {0.f, 0.f, 0.f, 0.f};

        #pragma unroll 1
        for (int nt = 0; nt < NTL; ++nt) {
            const int cur = nt & 1;
            if (nt + 1 < NTL) {
                STAGE3(WB + (size_t)(nt + 1) * 6144, &sw[cur ^ 1][0]);
                __builtin_amdgcn_sched_barrier(0);
                asm volatile("s_waitcnt vmcnt(3)" ::: "memory");
            } else {
                __builtin_amdgcn_sched_barrier(0);
                asm volatile("s_waitcnt vmcnt(0)" ::: "memory");
            }
            __syncthreads();

            const fp16* wbuf = (const fp16*)&sw[cur][0];
            f32x4 aH = {0,0,0,0}, aR = {0,0,0,0}, aT = {0,0,0,0};
            #pragma unroll
            for (int ks = 0; ks < 4; ++ks) {
                half8 wH = *(const half8*)(wbuf + (0 * 4 + ks) * 512 + l * 8);
                half8 wR = *(const half8*)(wbuf + (1 * 4 + ks) * 512 + l * 8);
                half8 wT = *(const half8*)(wbuf + (2 * 4 + ks) * 512 + l * 8);
                aH = MFMA16(HA[ks], wH, aH, 0, 0, 0);
                aR = MFMA16(RA[ks], wR, aR, 0, 0, 0);
                aT = MFMA16(TA[ks], wT, aT, 0, 0, 0);
            }
            // epilogue (bias folded in K): sc += r * tanh(h + t)
            #pragma unroll
            for (int g = 0; g < 4; ++g) {
                float s0 = aH[g] + aT[g];
                float e0 = __expf(2.f * s0);
                float t0 = 1.f - 2.f / (e0 + 1.f);
                sc[g] = fmaf(aR[g], t0, sc[g]);
            }
            __syncthreads();
        }

        // reduce over the 16 col-lanes (masks 1,2,4,8 keep lg fixed); store
        #pragma unroll
        for (int g = 0; g < 4; ++g) {
            float s = sc[g];
            s += __shfl_xor(s, 1); s += __shfl_xor(s, 2);
            s += __shfl_xor(s, 4); s += __shfl_xor(s, 8);
            if (lr == 0) score[wtile * 16 + lg * 4 + g] = s;
        }
    }
    grid_barrier(bar, 1);

    // ================= phase B: softmax + aggregation (grid-strided) ========
    for (int mybl = blockIdx.x; mybl < BB * LL; mybl += NBLK) {
        if (tid < 64) {
            const int t = tid;
            const bool valid = t < TT;
            float lgt = valid ? score[mybl * TT + t] : 0.f;
            const bool tm = valid ? (tmask[mybl * TT + t] != 0) : false;
            const bool pm = pmask[mybl] != 0;
            float logit = pm ? 0.f : (tm ? NEG_INF_F : lgt);
            float mx = valid ? logit : -3.0e38f;
            #pragma unroll
            for (int o = 32; o; o >>= 1) mx = fmaxf(mx, __shfl_xor(mx, o));
            float e = valid ? __expf(logit - mx) : 0.f;
            float s = e;
            #pragma unroll
            for (int o = 32; o; o >>= 1) s += __shfl_xor(s, o);
            if (valid) sattn[t] = e / s;
        }
        __syncthreads();
        if (tid < 2 * TE) {
            const size_t b2 = (size_t)mybl * TT * TE;
            const float* src = (tid < TE) ? head + b2 + tid
                                          : tail + b2 + (tid - TE);
            float acc = 0.f;
            #pragma unroll
            for (int t = 0; t < TT; ++t) acc = fmaf(src[t * TE], sattn[t], acc);
            out[(size_t)mybl * (2 * TE) + tid] = acc;
        }
        __syncthreads();   // sattn safe before next grid-stride iteration
    }
}

extern "C" void kernel_launch(void* const* d_in, const int* in_sizes, int n_in,
                              void* d_out, int out_size, void* d_ws, size_t ws_size,
                              hipStream_t stream) {
    const float* head = (const float*)d_in[0];
    const float* rel  = (const float*)d_in[1];
    const float* tail = (const float*)d_in[2];
    const float* Whw  = (const float*)d_in[3];
    const float* Whb  = (const float*)d_in[4];
    const float* Wrw  = (const float*)d_in[5];
    const float* Wrb  = (const float*)d_in[6];
    const float* Wtw  = (const float*)d_in[7];
    const float* Wtb  = (const float*)d_in[8];
    const int* tmask  = (const int*)d_in[9];
    const int* pmask  = (const int*)d_in[10];
    float* out = (float*)d_out;

    // ws layout: [0,256) barrier counters | [256,160000) WB fp16 | [160000,...) scores
    unsigned* bar = (unsigned*)d_ws;
    fp16* WB      = (fp16*)((char*)d_ws + 256);
    float* score  = (float*)((char*)d_ws + 256 + NWPREP * sizeof(fp16));

    hipMemsetAsync(d_ws, 0, 256, stream);   // zero barrier counters (capturable)
    ccm_fused_kernel<<<NBLK, 256, 0, stream>>>(head, rel, tail,
                                               Whw, Whb, Wrw, Wrb, Wtw, Wtb,
                                               tmask, pmask, out,
                                               bar, WB, score);
}

// Round 8
// 155.863 us; speedup vs baseline: 2.9666x; 2.9666x over previous
//
#include <hip/hip_runtime.h>
#include <math.h>

#define BB 16
#define LL 100
#define TT 50
#define TE 100
#define HH 200
#define NTL 13               // N tiles of 16 -> 208 (pad 8)
#define NWPREP (NTL * 3 * 2048)   // 79872 weight-fragment elements
#define NEG_INF_F (-1e30f)

typedef _Float16 fp16;
typedef fp16 half8 __attribute__((ext_vector_type(8)));
typedef float f32x4 __attribute__((ext_vector_type(4)));

#define MFMA16 __builtin_amdgcn_mfma_f32_16x16x32_f16

// ---------------------------------------------------------------------------
// Prep: W^T as fp16 MFMA B-fragments, bias folded in at k==100.
// Layout: idx = (((nt*3 + p)*4 + ks)*64 + lane)*8 + elem  (12 KB per nt-chunk)
//   k = ks*32 + 8*(lane>>4) + elem   (d index; k==100 holds bias; pad 0)
//   n = nt*16 + (lane&15)            (h index, zero-pad n>=200)
// ---------------------------------------------------------------------------
__global__ __launch_bounds__(256)
void wprep_kernel(const float* __restrict__ Wh, const float* __restrict__ Wr,
                  const float* __restrict__ Wt,
                  const float* __restrict__ Bh, const float* __restrict__ Br,
                  const float* __restrict__ Bt,
                  fp16* __restrict__ WB) {
    int idx = blockIdx.x * 256 + threadIdx.x;   // grid covers exactly NWPREP
    int elem = idx & 7;
    int lane = (idx >> 3) & 63;
    int ks   = (idx >> 9) & 3;
    int np   = idx >> 11;          // nt*3 + p
    int p    = np % 3;
    int nt   = np / 3;
    int k = ks * 32 + 8 * (lane >> 4) + elem;
    int n = nt * 16 + (lane & 15);
    const float* W  = (p == 0) ? Wh : (p == 1) ? Wr : Wt;
    const float* Bi = (p == 0) ? Bh : (p == 1) ? Br : Bt;
    float v = 0.0f;
    if (n < HH) {
        if (k < TE)       v = W[n * TE + k];
        else if (k == TE) v = Bi[n];           // bias row (A supplies 1.0)
    }
    WB[idx] = (fp16)v;
}

// A-fragment gather for one flat 16-row M-tile (rows always valid).
// ks==3 carries k=96..99 + bias-activation 1.0 @ k==100 (lg==0, elem 4).
// All array writes at compile-time indices (rule #20).
#define GATHER1(SRC, DST)                                                       \
    {                                                                           \
        _Pragma("unroll")                                                       \
        for (int ks_ = 0; ks_ < 4; ++ks_) {                                     \
            f32x4 v0 = {0.f, 0.f, 0.f, 0.f}, v1 = {0.f, 0.f, 0.f, 0.f};         \
            float one_ = 0.f;                                                   \
            if (ks_ < 3) {                                                      \
                const int d0 = ks_ * 32 + 8 * lg;                               \
                v0 = *(const f32x4*)((SRC) + d0);                               \
                v1 = *(const f32x4*)((SRC) + d0 + 4);                           \
            } else if (lg == 0) {                                               \
                v0 = *(const f32x4*)((SRC) + 96);                               \
                one_ = 1.0f;                                                    \
            }                                                                   \
            half8 h8;                                                           \
            _Pragma("unroll")                                                   \
            for (int i_ = 0; i_ < 4; ++i_) {                                    \
                h8[i_]     = (fp16)v0[i_];                                      \
                h8[4 + i_] = (fp16)v1[i_];                                      \
            }                                                                   \
            if (ks_ == 3) h8[4] = (fp16)one_;   /* k==100 activation */         \
            DST[ks_] = h8;                                                      \
        }                                                                       \
    }

// Stage 3 of the 12 1-KB units of one nt weight chunk (this wave's share).
#define STAGE3(GBASE, LBASE)                                                    \
    {                                                                           \
        _Pragma("unroll")                                                       \
        for (int u_ = 0; u_ < 3; ++u_) {                                        \
            const int unit_ = wv * 3 + u_;                                      \
            __builtin_amdgcn_global_load_lds(                                   \
                (const __attribute__((address_space(1))) unsigned int*)         \
                    ((GBASE) + unit_ * 512 + l * 8),                            \
                (__attribute__((address_space(3))) unsigned int*)               \
                    ((LBASE) + unit_ * 512),                                    \
                16, 0, 0);                                                      \
        }                                                                       \
    }

// ---------------------------------------------------------------------------
// Flat-M GEMM + fused score: wave -> one 16-row M-tile of the 80000-row
// flattened (bl,t) dimension. 1250 blocks x 4 waves = 5000 tiles exactly.
// ---------------------------------------------------------------------------
__global__ __launch_bounds__(256, 5)
void ccm_gemm_kernel(const float* __restrict__ head, const float* __restrict__ rel,
                     const float* __restrict__ tail,
                     const fp16* __restrict__ WB,
                     float* __restrict__ score) {
    __shared__ fp16 sw[2][6144];      // double-buffered nt chunk (12 KB each)

    const int tid = threadIdx.x;
    const int wv  = tid >> 6;         // wave 0..3
    const int l   = tid & 63;
    const int lr  = l & 15;           // A row-in-tile / D col
    const int lg  = l >> 4;           // k-group / D row-group

    const int wtile = blockIdx.x * 4 + wv;
    const size_t abase = ((size_t)wtile * 16 + lr) * TE;

    half8 HA[4], RA[4], TA[4];
    GATHER1(head + abase, HA);
    GATHER1(rel  + abase, RA);
    GATHER1(tail + abase, TA);

    STAGE3(WB, &sw[0][0]);

    float sc[4] = {0.f, 0.f, 0.f, 0.f};

    #pragma unroll 1
    for (int nt = 0; nt < NTL; ++nt) {
        const int cur = nt & 1;
        if (nt + 1 < NTL) {
            STAGE3(WB + (size_t)(nt + 1) * 6144, &sw[cur ^ 1][0]);
            __builtin_amdgcn_sched_barrier(0);
            asm volatile("s_waitcnt vmcnt(3)" ::: "memory");  // my buf[cur] units done
        } else {
            __builtin_amdgcn_sched_barrier(0);
            asm volatile("s_waitcnt vmcnt(0)" ::: "memory");
        }
        __syncthreads();                                      // all units visible

        const fp16* wbuf = (const fp16*)&sw[cur][0];
        f32x4 aH = {0,0,0,0}, aR = {0,0,0,0}, aT = {0,0,0,0};
        #pragma unroll
        for (int ks = 0; ks < 4; ++ks) {
            half8 wH = *(const half8*)(wbuf + (0 * 4 + ks) * 512 + l * 8);
            half8 wR = *(const half8*)(wbuf + (1 * 4 + ks) * 512 + l * 8);
            half8 wT = *(const half8*)(wbuf + (2 * 4 + ks) * 512 + l * 8);
            aH = MFMA16(HA[ks], wH, aH, 0, 0, 0);
            aR = MFMA16(RA[ks], wR, aR, 0, 0, 0);
            aT = MFMA16(TA[ks], wT, aT, 0, 0, 0);
        }
        // epilogue (bias folded in K): sc += r * tanh(h + t)
        #pragma unroll
        for (int g = 0; g < 4; ++g) {
            float s0 = aH[g] + aT[g];
            float e0 = __expf(2.f * s0);
            float t0 = 1.f - 2.f / (e0 + 1.f);
            sc[g] = fmaf(aR[g], t0, sc[g]);
        }
        __syncthreads();                                      // reads done pre-overwrite
    }

    // reduce over the 16 col-lanes (masks 1,2,4,8 keep lg fixed); store score
    #pragma unroll
    for (int g = 0; g < 4; ++g) {
        float s = sc[g];
        s += __shfl_xor(s, 1); s += __shfl_xor(s, 2);
        s += __shfl_xor(s, 4); s += __shfl_xor(s, 8);
        if (lr == 0) score[wtile * 16 + lg * 4 + g] = s;
    }
}

// ---------------------------------------------------------------------------
// Softmax over T + weighted entity aggregation. One (b,l) per block.
// ---------------------------------------------------------------------------
__global__ __launch_bounds__(256)
void ccm_softagg_kernel(const float* __restrict__ head, const float* __restrict__ tail,
                        const float* __restrict__ score,
                        const int* __restrict__ tmask, const int* __restrict__ pmask,
                        float* __restrict__ out) {
    __shared__ float sattn[64];
    const int bl  = blockIdx.x;
    const int tid = threadIdx.x;

    if (tid < 64) {
        const int t = tid;
        const bool valid = t < TT;
        float lgt = valid ? score[bl * TT + t] : 0.f;
        const bool tm = valid ? (tmask[bl * TT + t] != 0) : false;
        const bool pm = pmask[bl] != 0;
        float logit = pm ? 0.f : (tm ? NEG_INF_F : lgt);
        float mx = valid ? logit : -3.0e38f;
        #pragma unroll
        for (int o = 32; o; o >>= 1) mx = fmaxf(mx, __shfl_xor(mx, o));
        float e = valid ? __expf(logit - mx) : 0.f;
        float s = e;
        #pragma unroll
        for (int o = 32; o; o >>= 1) s += __shfl_xor(s, o);
        if (valid) sattn[t] = e / s;
    }
    __syncthreads();

    if (tid < 2 * TE) {
        const size_t b2 = (size_t)bl * TT * TE;
        const float* src = (tid < TE) ? head + b2 + tid
                                      : tail + b2 + (tid - TE);
        float acc = 0.f;
        #pragma unroll
        for (int t = 0; t < TT; ++t) acc = fmaf(src[t * TE], sattn[t], acc);
        out[(size_t)bl * (2 * TE) + tid] = acc;
    }
}

extern "C" void kernel_launch(void* const* d_in, const int* in_sizes, int n_in,
                              void* d_out, int out_size, void* d_ws, size_t ws_size,
                              hipStream_t stream) {
    const float* head = (const float*)d_in[0];
    const float* rel  = (const float*)d_in[1];
    const float* tail = (const float*)d_in[2];
    const float* Whw  = (const float*)d_in[3];
    const float* Whb  = (const float*)d_in[4];
    const float* Wrw  = (const float*)d_in[5];
    const float* Wrb  = (const float*)d_in[6];
    const float* Wtw  = (const float*)d_in[7];
    const float* Wtb  = (const float*)d_in[8];
    const int* tmask  = (const int*)d_in[9];
    const int* pmask  = (const int*)d_in[10];
    float* out = (float*)d_out;

    // ws layout: WB fp16 fragments | scores f32
    fp16* WB     = (fp16*)d_ws;
    float* score = (float*)((char*)d_ws + NWPREP * sizeof(fp16));

    wprep_kernel<<<NWPREP / 256, 256, 0, stream>>>(Whw, Wrw, Wtw,
                                                   Whb, Wrb, Wtb, WB);
    ccm_gemm_kernel<<<1250, 256, 0, stream>>>(head, rel, tail, WB, score);
    ccm_softagg_kernel<<<BB * LL, 256, 0, stream>>>(head, tail, score,
                                                    tmask, pmask, out);
}